// Round 1
// 16304.738 us; speedup vs baseline: 1.1549x; 1.1549x over previous
//
#include <hip/hip_runtime.h>

// SNLI attention-LSTM, MI355X. Round 1: all GEMM flops moved to split-bf16
// (hi/lo) 3-pass MFMA (err ~2^-16/product, keeps fp32-level absmax).
// - lstm_step_mfma: fused gather + [emb|h] @ Wcat^T + cell, no LDS,
//   direct 16B global fragment loads; weights packed [4096][1344] hi/lo,
//   L2-resident across the 192-step scan. Gate-grouped columns keep the
//   cell epilogue thread-local (C layout: col=lane&15,row=(lane>>4)*4+reg).
// - gemm_mfma: Y@wy, outh@wh from pre-split A (written by step epilogue).
// - attention scan kernels unchanged except r_update reads split Y, grid (B,2).

using u16 = unsigned short;
typedef short bf16x8 __attribute__((ext_vector_type(8)));
typedef float f32x4 __attribute__((ext_vector_type(4)));

constexpr int B  = 128;
constexpr int SP = 128;
constexpr int SH = 64;
constexpr int H  = 1024;
constexpr int E  = 300;
constexpr int NC = 4;
constexpr int G4H  = 4 * H;          // 4096
constexpr int EPAD = 320;            // E padded to multiple of 32
constexpr int KCAT = EPAD + H;       // 1344

__device__ __forceinline__ float sigf(float x) { return 1.0f / (1.0f + __expf(-x)); }
__device__ __forceinline__ float tanh_fast(float x) {
    float e = __expf(2.0f * x);
    return 1.0f - 2.0f / (e + 1.0f);
}
__device__ __forceinline__ u16 f2bf(float x) {           // round-to-nearest-even
    union { float f; unsigned u; } v; v.f = x;
    unsigned r = v.u + 0x7fffu + ((v.u >> 16) & 1u);
    return (u16)(r >> 16);
}
__device__ __forceinline__ float bf2f(u16 h) {
    union { unsigned u; float f; } v; v.u = ((unsigned)h) << 16;
    return v.f;
}
__device__ __forceinline__ f32x4 mfma16(bf16x8 a, bf16x8 b, f32x4 c) {
    return __builtin_amdgcn_mfma_f32_16x16x32_bf16(a, b, c, 0, 0, 0);
}

// ---------------------------------------------------------------------------
// Prep: split [w_ih | 0pad | w_hh] row-major [4096][1344] into bf16 hi/lo.
// ---------------------------------------------------------------------------
__global__ __launch_bounds__(256)
void wcat_split_kernel(const float* __restrict__ w_ih, const float* __restrict__ w_hh,
                       u16* __restrict__ dh, u16* __restrict__ dl)
{
    int col = blockIdx.x * 256 + threadIdx.x;
    int n = blockIdx.y;
    if (col >= KCAT) return;
    float v = 0.f;
    if (col < E)          v = w_ih[(size_t)n * E + col];
    else if (col >= EPAD) v = w_hh[(size_t)n * H + (col - EPAD)];
    u16 hi = f2bf(v);
    dh[(size_t)n * KCAT + col] = hi;
    dl[(size_t)n * KCAT + col] = f2bf(v - bf2f(hi));
}

// Prep: dst[n][k] = split(src[k][n]) for square H x H weights (wy, wh).
__global__ __launch_bounds__(256)
void tsplit_kernel(const float* __restrict__ src, u16* __restrict__ dh, u16* __restrict__ dl)
{
    int k = blockIdx.x * 256 + threadIdx.x;   // 0..H-1, coalesced writes
    int n = blockIdx.y;
    float v = src[(size_t)k * H + n];
    u16 hi = f2bf(v);
    dh[(size_t)n * H + k] = hi;
    dl[(size_t)n * H + k] = f2bf(v - bf2f(hi));
}

// ---------------------------------------------------------------------------
// Fused LSTM step, split-bf16 MFMA.
// grid (64, 2), 256 thr. Block: rows m0..m0+63, hidden units k0..k0+15, all
// 4 gates. Wave w owns m-tile m0+16w; per k-step: 10x16B loads, 12 MFMA.
// ---------------------------------------------------------------------------
template<int PREMISE>
__global__ __launch_bounds__(256)
void lstm_step_mfma(const int* __restrict__ toks, int t, int S,
                    const float* __restrict__ emb,
                    const u16* __restrict__ Wh, const u16* __restrict__ Wl,
                    const float* __restrict__ b_ih, const float* __restrict__ b_hh,
                    const u16* __restrict__ hin_hi, const u16* __restrict__ hin_lo,
                    u16* __restrict__ hout_hi, u16* __restrict__ hout_lo,
                    float* __restrict__ c, float* __restrict__ hmask,
                    float* __restrict__ cmask,
                    u16* __restrict__ seq_hi, u16* __restrict__ seq_lo)
{
    const int tid  = threadIdx.x;
    const int lane = tid & 63;
    const int wave = tid >> 6;
    const int l15  = lane & 15;
    const int lk8  = (lane >> 4) * 8;
    const int k0   = blockIdx.x * 16;
    const int m0   = blockIdx.y * 64 + wave * 16;
    const int arow = m0 + l15;
    const int tok  = toks[arow * S + t];

    const u16* bhp[4]; const u16* blp[4];
#pragma unroll
    for (int g = 0; g < 4; ++g) {
        size_t o = (size_t)(g * H + k0 + l15) * KCAT + lk8;
        bhp[g] = Wh + o; blp[g] = Wl + o;
    }

    f32x4 acc[4] = {{0.f,0.f,0.f,0.f},{0.f,0.f,0.f,0.f},
                    {0.f,0.f,0.f,0.f},{0.f,0.f,0.f,0.f}};

    // ---- emb segment (K cols 0..319): gather row, split on the fly ----
    const float* ea = emb + (size_t)tok * E + lk8;
    for (int ks = 0; ks < 9; ++ks) {
        float4 f0 = *(const float4*)(ea + ks * 32);
        float4 f1 = *(const float4*)(ea + ks * 32 + 4);
        float v[8] = {f0.x, f0.y, f0.z, f0.w, f1.x, f1.y, f1.z, f1.w};
        bf16x8 a_hi, a_lo;
#pragma unroll
        for (int j = 0; j < 8; ++j) {
            u16 hi = f2bf(v[j]);
            a_hi[j] = (short)hi;
            a_lo[j] = (short)f2bf(v[j] - bf2f(hi));
        }
#pragma unroll
        for (int g = 0; g < 4; ++g) {
            bf16x8 w_h = *(const bf16x8*)(bhp[g] + ks * 32);
            bf16x8 w_l = *(const bf16x8*)(blp[g] + ks * 32);
            acc[g] = mfma16(a_hi, w_h, acc[g]);
            acc[g] = mfma16(a_lo, w_h, acc[g]);
            acc[g] = mfma16(a_hi, w_l, acc[g]);
        }
    }
    {   // ks = 9: k = 288 + lk8 + j, valid only while < 300 (Wcat pad is 0)
        float v[8];
#pragma unroll
        for (int j = 0; j < 8; ++j) {
            int k = 288 + lk8 + j;
            v[j] = (k < E) ? emb[(size_t)tok * E + k] : 0.f;
        }
        bf16x8 a_hi, a_lo;
#pragma unroll
        for (int j = 0; j < 8; ++j) {
            u16 hi = f2bf(v[j]);
            a_hi[j] = (short)hi;
            a_lo[j] = (short)f2bf(v[j] - bf2f(hi));
        }
#pragma unroll
        for (int g = 0; g < 4; ++g) {
            bf16x8 w_h = *(const bf16x8*)(bhp[g] + 9 * 32);
            bf16x8 w_l = *(const bf16x8*)(blp[g] + 9 * 32);
            acc[g] = mfma16(a_hi, w_h, acc[g]);
            acc[g] = mfma16(a_lo, w_h, acc[g]);
            acc[g] = mfma16(a_hi, w_l, acc[g]);
        }
    }

    // ---- h segment (K cols 320..1343): pre-split h from previous step ----
    const u16* hhp = hin_hi + (size_t)arow * H + lk8;
    const u16* hlp = hin_lo + (size_t)arow * H + lk8;
#pragma unroll 2
    for (int ks = 0; ks < 32; ++ks) {
        bf16x8 a_hi = *(const bf16x8*)(hhp + ks * 32);
        bf16x8 a_lo = *(const bf16x8*)(hlp + ks * 32);
#pragma unroll
        for (int g = 0; g < 4; ++g) {
            bf16x8 w_h = *(const bf16x8*)(bhp[g] + EPAD + ks * 32);
            bf16x8 w_l = *(const bf16x8*)(blp[g] + EPAD + ks * 32);
            acc[g] = mfma16(a_hi, w_h, acc[g]);
            acc[g] = mfma16(a_lo, w_h, acc[g]);
            acc[g] = mfma16(a_hi, w_l, acc[g]);
        }
    }

    // ---- cell epilogue: lane owns all 4 gates of (m, k) ----
    const int k = k0 + l15;
    float bs[4];
#pragma unroll
    for (int g = 0; g < 4; ++g) bs[g] = b_ih[g * H + k] + b_hh[g * H + k];
#pragma unroll
    for (int j = 0; j < 4; ++j) {
        int m = m0 + (lane >> 4) * 4 + j;
        size_t idx = (size_t)m * H + k;
        float gi = acc[0][j] + bs[0];
        float gf = acc[1][j] + bs[1];
        float gg = acc[2][j] + bs[2];
        float go = acc[3][j] + bs[3];
        float c2 = sigf(gf) * c[idx] + sigf(gi) * tanh_fast(gg);
        float h2 = sigf(go) * tanh_fast(c2);
        c[idx] = c2;
        u16 h2h = f2bf(h2);
        hout_hi[idx] = h2h;
        hout_lo[idx] = f2bf(h2 - bf2f(h2h));
        float mt = (toks[m * S + t] != 0) ? 1.f : 0.f;
        float hmv = mt * h2 + (1.f - mt) * hmask[idx];
        hmask[idx] = hmv;
        u16 mh = f2bf(hmv);
        u16 ml = f2bf(hmv - bf2f(mh));
        if (PREMISE) {
            float cmv = mt * c2 + (1.f - mt) * cmask[idx];
            cmask[idx] = cmv;
            size_t yi = ((size_t)m * SP + t) * H + k;   // Y [B][SP][H]
            seq_hi[yi] = mh; seq_lo[yi] = ml;
        } else {
            size_t oi = ((size_t)t * B + m) * H + k;    // outh [SH][B][H]
            seq_hi[oi] = mh; seq_lo[oi] = ml;
        }
    }
}

// ---------------------------------------------------------------------------
// Split-bf16 MFMA GEMM: C[M,N] = A[M,K] @ B^T where B stored [N][K] hi/lo.
// grid (N/64, M/64), 256 thr; wave = 16 rows x 64 cols (4 n-tiles).
// ---------------------------------------------------------------------------
__global__ __launch_bounds__(256)
void gemm_mfma_kernel(const u16* __restrict__ Ah, const u16* __restrict__ Al,
                      const u16* __restrict__ Bh, const u16* __restrict__ Bl,
                      float* __restrict__ C, int M, int N, int K)
{
    const int tid  = threadIdx.x;
    const int lane = tid & 63;
    const int wave = tid >> 6;
    const int l15  = lane & 15;
    const int lk8  = (lane >> 4) * 8;
    const int m0   = blockIdx.y * 64 + wave * 16;
    const int n0   = blockIdx.x * 64;

    const u16* ahp = Ah + (size_t)(m0 + l15) * K + lk8;
    const u16* alp = Al + (size_t)(m0 + l15) * K + lk8;
    const u16* bhp[4]; const u16* blp[4];
#pragma unroll
    for (int nt = 0; nt < 4; ++nt) {
        size_t o = (size_t)(n0 + nt * 16 + l15) * K + lk8;
        bhp[nt] = Bh + o; blp[nt] = Bl + o;
    }
    f32x4 acc[4] = {{0.f,0.f,0.f,0.f},{0.f,0.f,0.f,0.f},
                    {0.f,0.f,0.f,0.f},{0.f,0.f,0.f,0.f}};
    const int nks = K >> 5;
#pragma unroll 2
    for (int ks = 0; ks < nks; ++ks) {
        bf16x8 a_hi = *(const bf16x8*)(ahp + ks * 32);
        bf16x8 a_lo = *(const bf16x8*)(alp + ks * 32);
#pragma unroll
        for (int nt = 0; nt < 4; ++nt) {
            bf16x8 b_hi = *(const bf16x8*)(bhp[nt] + ks * 32);
            bf16x8 b_lo = *(const bf16x8*)(blp[nt] + ks * 32);
            acc[nt] = mfma16(a_hi, b_hi, acc[nt]);
            acc[nt] = mfma16(a_lo, b_hi, acc[nt]);
            acc[nt] = mfma16(a_hi, b_lo, acc[nt]);
        }
    }
#pragma unroll
    for (int nt = 0; nt < 4; ++nt)
#pragma unroll
        for (int j = 0; j < 4; ++j) {
            int m = m0 + (lane >> 4) * 4 + j;
            C[(size_t)m * N + n0 + nt * 16 + l15] = acc[nt][j];
        }
}

// ---------------------------------------------------------------------------
// Skinny fp32 GEMM (M=128): tile 32x64, BK=16, 256 threads, dbuf (unchanged).
// ---------------------------------------------------------------------------
template<bool ACC>
__global__ __launch_bounds__(256)
void skinny_kernel(const float* __restrict__ A,
                   const float* __restrict__ B1, float* __restrict__ C1,
                   const float* __restrict__ B2, float* __restrict__ C2,
                   int K, int N, int ntiles)
{
    const int tid = threadIdx.x;
    const int tx = tid & 15, ty = tid >> 4;
    const int bx = blockIdx.x;
    const float* Bw = (bx < ntiles) ? B1 : B2;
    float* C       = (bx < ntiles) ? C1 : C2;
    const int n0 = ((bx < ntiles) ? bx : bx - ntiles) * 64;
    const int m0 = blockIdx.y * 32;

    __shared__ float As[2][16][34];
    __shared__ float Bs[2][16][68];
    const int sq = tid & 15, sm = tid >> 4;
    const int nb = tid & 63, kb = tid >> 6;

    float ra[2], rb[4];
    auto ldA = [&](int k0, int r) -> float {
        return A[(size_t)(m0 + sm + 16 * r) * K + k0 + sq];
    };
    auto ldB = [&](int k0, int r) -> float {
        return Bw[(size_t)(k0 + kb + 4 * r) * N + n0 + nb];
    };

    float acc[2][4] = {};
    ra[0] = ldA(0, 0); ra[1] = ldA(0, 1);
#pragma unroll
    for (int r = 0; r < 4; ++r) rb[r] = ldB(0, r);
    As[0][sq][sm] = ra[0]; As[0][sq][sm + 16] = ra[1];
#pragma unroll
    for (int r = 0; r < 4; ++r) Bs[0][kb + 4 * r][nb] = rb[r];
    __syncthreads();

    const int NKT = K / 16;
    for (int kt = 0; kt < NKT; ++kt) {
        const int buf = kt & 1;
        if (kt + 1 < NKT) {
            int k0 = (kt + 1) * 16;
            ra[0] = ldA(k0, 0); ra[1] = ldA(k0, 1);
#pragma unroll
            for (int r = 0; r < 4; ++r) rb[r] = ldB(k0, r);
        }
#pragma unroll
        for (int qq = 0; qq < 16; ++qq) {
            float2 a2 = *(const float2*)&As[buf][qq][ty * 2];
            float4 b4 = *(const float4*)&Bs[buf][qq][tx * 4];
            acc[0][0] += a2.x * b4.x; acc[0][1] += a2.x * b4.y;
            acc[0][2] += a2.x * b4.z; acc[0][3] += a2.x * b4.w;
            acc[1][0] += a2.y * b4.x; acc[1][1] += a2.y * b4.y;
            acc[1][2] += a2.y * b4.z; acc[1][3] += a2.y * b4.w;
        }
        if (kt + 1 < NKT) {
            const int nbuf = buf ^ 1;
            As[nbuf][sq][sm] = ra[0]; As[nbuf][sq][sm + 16] = ra[1];
#pragma unroll
            for (int r = 0; r < 4; ++r) Bs[nbuf][kb + 4 * r][nb] = rb[r];
            __syncthreads();
        }
    }
#pragma unroll
    for (int i = 0; i < 2; ++i) {
        int m = m0 + ty * 2 + i;
        float* cp = &C[(size_t)m * N + n0 + tx * 4];
        float4 v = make_float4(acc[i][0], acc[i][1], acc[i][2], acc[i][3]);
        if (ACC) {
            float4 o = *(const float4*)cp;
            v.x += o.x; v.y += o.y; v.z += o.z; v.w += o.w;
        }
        *(float4*)cp = v;
    }
}

// ---------------------------------------------------------------------------
// score: s[b,p] = sum_h tanh(first + hsec_t + secr) * w  (+pad mask)
// ---------------------------------------------------------------------------
__global__ __launch_bounds__(256)
void score_kernel(const float* __restrict__ first,
                  const float* __restrict__ hsec_t,
                  const float* __restrict__ secr,
                  const float* __restrict__ w,
                  const int* __restrict__ ptoks,
                  float* __restrict__ s)
{
    const int bp = blockIdx.x;
    const int b = bp >> 7;
    const float* fr = first + (size_t)bp * H;
    const float* hs = hsec_t + (size_t)b * H;
    const float* sr = secr + (size_t)b * H;
    float acc = 0.f;
#pragma unroll
    for (int j = 0; j < 4; ++j) {
        int k = threadIdx.x + j * 256;
        acc += tanh_fast(fr[k] + hs[k] + sr[k]) * w[k];
    }
    for (int off = 32; off > 0; off >>= 1) acc += __shfl_down(acc, off);
    __shared__ float red[4];
    if ((threadIdx.x & 63) == 0) red[threadIdx.x >> 6] = acc;
    __syncthreads();
    if (threadIdx.x == 0) {
        float v = red[0] + red[1] + red[2] + red[3];
        int p = bp & 127;
        s[bp] = v + ((ptoks[b * SP + p] != 0) ? 0.f : -1000.f);
    }
}

// ---------------------------------------------------------------------------
// r_update: softmax(s) @ Y (split bf16) + tanh(rwt), masked carry into r.
// grid (B, 2): each block handles 512 of the 1024 H-columns.
// ---------------------------------------------------------------------------
__global__ __launch_bounds__(256)
void r_update_kernel(const float* __restrict__ s,
                     const u16* __restrict__ Yh, const u16* __restrict__ Yl,
                     const float* __restrict__ rwt,
                     const int* __restrict__ htoks, int t,
                     float* __restrict__ r)
{
    const int b = blockIdx.x, tid = threadIdx.x;
    const int kbase = blockIdx.y * 512;
    __shared__ float al[SP];
    __shared__ float red[SP];
    if (tid < SP) { al[tid] = s[b * SP + tid]; red[tid] = al[tid]; }
    __syncthreads();
    for (int off = 64; off > 0; off >>= 1) {
        if (tid < off) red[tid] = fmaxf(red[tid], red[tid + off]);
        __syncthreads();
    }
    float mx = red[0];
    __syncthreads();
    if (tid < SP) { al[tid] = __expf(al[tid] - mx); red[tid] = al[tid]; }
    __syncthreads();
    for (int off = 64; off > 0; off >>= 1) {
        if (tid < off) red[tid] += red[tid + off];
        __syncthreads();
    }
    float inv = 1.f / red[0];
    __syncthreads();
    if (tid < SP) al[tid] *= inv;
    __syncthreads();

    float acc0 = 0.f, acc1 = 0.f;
    const size_t ybase = (size_t)b * SP * H + kbase + tid;
    for (int p = 0; p < SP; ++p) {
        float a = al[p];
        size_t o = ybase + (size_t)p * H;
        acc0 += a * (bf2f(Yh[o])       + bf2f(Yl[o]));
        acc1 += a * (bf2f(Yh[o + 256]) + bf2f(Yl[o + 256]));
    }
    float mt = (htoks[b * SH + t] != 0) ? 1.f : 0.f;
    int k = kbase + tid;
    float rn0 = acc0 + tanh_fast(rwt[(size_t)b * H + k]);
    float rn1 = acc1 + tanh_fast(rwt[(size_t)b * H + k + 256]);
    r[(size_t)b * H + k]       = mt * rn0 + (1.f - mt) * r[(size_t)b * H + k];
    r[(size_t)b * H + k + 256] = mt * rn1 + (1.f - mt) * r[(size_t)b * H + k + 256];
}

// logits -> softmax over 4 classes
__global__ __launch_bounds__(256)
void final_kernel(const float* __restrict__ pre,
                  const float* __restrict__ fc_w,
                  const float* __restrict__ fc_b,
                  float* __restrict__ out)
{
    int b = blockIdx.x;
    float acc[NC] = {0.f, 0.f, 0.f, 0.f};
    for (int k = threadIdx.x; k < H; k += 256) {
        float hs = tanh_fast(pre[(size_t)b * H + k]);
#pragma unroll
        for (int cc = 0; cc < NC; ++cc) acc[cc] += hs * fc_w[cc * H + k];
    }
    __shared__ float red[NC][256];
#pragma unroll
    for (int cc = 0; cc < NC; ++cc) red[cc][threadIdx.x] = acc[cc];
    __syncthreads();
    for (int off = 128; off > 0; off >>= 1) {
        if (threadIdx.x < off)
#pragma unroll
            for (int cc = 0; cc < NC; ++cc)
                red[cc][threadIdx.x] += red[cc][threadIdx.x + off];
        __syncthreads();
    }
    if (threadIdx.x == 0) {
        float l[NC], mx = -1e30f;
#pragma unroll
        for (int cc = 0; cc < NC; ++cc) { l[cc] = red[cc][0] + fc_b[cc]; mx = fmaxf(mx, l[cc]); }
        float sum = 0.f;
#pragma unroll
        for (int cc = 0; cc < NC; ++cc) { l[cc] = __expf(l[cc] - mx); sum += l[cc]; }
#pragma unroll
        for (int cc = 0; cc < NC; ++cc) out[b * NC + cc] = l[cc] / sum;
    }
}

extern "C" void kernel_launch(void* const* d_in, const int* in_sizes, int n_in,
                              void* d_out, int out_size, void* d_ws, size_t ws_size,
                              hipStream_t stream)
{
    const int*   prem   = (const int*)d_in[0];
    const int*   hyp    = (const int*)d_in[1];
    const float* emb    = (const float*)d_in[2];
    const float* w_ih_p = (const float*)d_in[3];
    const float* w_hh_p = (const float*)d_in[4];
    const float* b_ih_p = (const float*)d_in[5];
    const float* b_hh_p = (const float*)d_in[6];
    const float* w_ih_h = (const float*)d_in[7];
    const float* w_hh_h = (const float*)d_in[8];
    const float* b_ih_h = (const float*)d_in[9];
    const float* b_hh_h = (const float*)d_in[10];
    const float* wy     = (const float*)d_in[11];
    const float* wh     = (const float*)d_in[12];
    const float* wr     = (const float*)d_in[13];
    const float* wv     = (const float*)d_in[14];
    const float* wt     = (const float*)d_in[15];
    const float* wp     = (const float*)d_in[16];
    const float* wx     = (const float*)d_in[17];
    const float* fc_w   = (const float*)d_in[18];
    const float* fc_b   = (const float*)d_in[19];
    float* out = (float*)d_out;
    (void)in_sizes; (void)n_in; (void)out_size; (void)ws_size;

    char* wsc = (char*)d_ws;
    size_t off = 0;
    auto alloc = [&](size_t bytes) -> void* {
        void* p = wsc + off;
        off += (bytes + 255) & ~(size_t)255;
        return p;
    };
    // split weight packs
    u16* Wp_hi  = (u16*)alloc((size_t)G4H * KCAT * 2);
    u16* Wp_lo  = (u16*)alloc((size_t)G4H * KCAT * 2);
    u16* Wq_hi  = (u16*)alloc((size_t)G4H * KCAT * 2);
    u16* Wq_lo  = (u16*)alloc((size_t)G4H * KCAT * 2);
    u16* wyT_hi = (u16*)alloc((size_t)H * H * 2);
    u16* wyT_lo = (u16*)alloc((size_t)H * H * 2);
    u16* whT_hi = (u16*)alloc((size_t)H * H * 2);
    u16* whT_lo = (u16*)alloc((size_t)H * H * 2);
    // sequence outputs (pre-split)
    u16* Y_hi  = (u16*)alloc((size_t)B * SP * H * 2);
    u16* Y_lo  = (u16*)alloc((size_t)B * SP * H * 2);
    u16* OH_hi = (u16*)alloc((size_t)SH * B * H * 2);
    u16* OH_lo = (u16*)alloc((size_t)SH * B * H * 2);
    float* first = (float*)alloc((size_t)B * SP * H * 4);
    float* hsec  = (float*)alloc((size_t)SH * B * H * 4);
    // h ping-pong (split) — contiguous for one memset
    const size_t BH = (size_t)B * H;
    u16* hA_hi = (u16*)alloc(BH * 2);
    u16* hA_lo = (u16*)alloc(BH * 2);
    u16* hB_hi = (u16*)alloc(BH * 2);
    u16* hB_lo = (u16*)alloc(BH * 2);
    // c, hm, cm contiguous for one memset
    float* cbuf = (float*)alloc(BH * 4);
    float* hm   = (float*)alloc(BH * 4);
    float* cm   = (float*)alloc(BH * 4);
    float* r    = (float*)alloc(BH * 4);
    float* secr = (float*)alloc(BH * 4);
    float* rwt  = (float*)alloc(BH * 4);
    float* pre  = (float*)alloc(BH * 4);
    float* sc   = (float*)alloc((size_t)B * SP * 4);

    // -------- one-time weight splits --------
    dim3 gW((KCAT + 255) / 256, G4H);
    wcat_split_kernel<<<gW, 256, 0, stream>>>(w_ih_p, w_hh_p, Wp_hi, Wp_lo);
    wcat_split_kernel<<<gW, 256, 0, stream>>>(w_ih_h, w_hh_h, Wq_hi, Wq_lo);
    tsplit_kernel<<<dim3(H / 256, H), 256, 0, stream>>>(wy, wyT_hi, wyT_lo);
    tsplit_kernel<<<dim3(H / 256, H), 256, 0, stream>>>(wh, whT_hi, whT_lo);

    hipMemsetAsync(hA_hi, 0, 4 * BH * 2, stream);   // hA_hi..hB_lo
    hipMemsetAsync(cbuf, 0, 3 * BH * 4, stream);    // c, hm, cm

    // -------- premise LSTM --------
    {
        u16 *ih = hA_hi, *il = hA_lo, *oh = hB_hi, *ol = hB_lo;
        for (int t = 0; t < SP; ++t) {
            lstm_step_mfma<1><<<dim3(64, 2), 256, 0, stream>>>(
                prem, t, SP, emb, Wp_hi, Wp_lo, b_ih_p, b_hh_p,
                ih, il, oh, ol, cbuf, hm, cm, Y_hi, Y_lo);
            u16* t1 = ih; ih = oh; oh = t1;
            u16* t2 = il; il = ol; ol = t2;
        }
    }

    // -------- hypothesis LSTM: h=0, c = cm (masked last premise cell) --------
    hipMemsetAsync(hA_hi, 0, 4 * BH * 2, stream);
    hipMemsetAsync(hm, 0, BH * 4, stream);
    {
        u16 *ih = hA_hi, *il = hA_lo, *oh = hB_hi, *ol = hB_lo;
        for (int t = 0; t < SH; ++t) {
            lstm_step_mfma<0><<<dim3(64, 2), 256, 0, stream>>>(
                hyp, t, SH, emb, Wq_hi, Wq_lo, b_ih_h, b_hh_h,
                ih, il, oh, ol, cm, hm, (float*)nullptr, OH_hi, OH_lo);
            u16* t1 = ih; ih = oh; oh = t1;
            u16* t2 = il; il = ol; ol = t2;
        }
    }
    // hm = out_h_last

    // -------- hoisted GEMMs (split-bf16 MFMA) --------
    gemm_mfma_kernel<<<dim3(H / 64, (B * SP) / 64), 256, 0, stream>>>(
        Y_hi, Y_lo, wyT_hi, wyT_lo, first, B * SP, H, H);
    gemm_mfma_kernel<<<dim3(H / 64, (SH * B) / 64), 256, 0, stream>>>(
        OH_hi, OH_lo, whT_hi, whT_lo, hsec, SH * B, H, H);

    // -------- attention scan --------
    hipMemsetAsync(r, 0, BH * 4, stream);
    for (int t = 0; t < SH; ++t) {
        skinny_kernel<false><<<dim3(32, 4), 256, 0, stream>>>(r, wr, secr, wt, rwt, H, H, 16);
        score_kernel<<<B * SP, 256, 0, stream>>>(first, hsec + (size_t)t * B * H, secr, wv, prem, sc);
        r_update_kernel<<<dim3(B, 2), 256, 0, stream>>>(sc, Y_hi, Y_lo, rwt, hyp, t, r);
    }

    // -------- final projection + softmax --------
    skinny_kernel<false><<<dim3(16, 4), 256, 0, stream>>>(r,  wp, pre, nullptr, nullptr, H, H, 16);
    skinny_kernel<true ><<<dim3(16, 4), 256, 0, stream>>>(hm, wx, pre, nullptr, nullptr, H, H, 16);
    final_kernel<<<B, 256, 0, stream>>>(pre, fc_w, fc_b, out);
}